// Round 2
// baseline (442.958 us; speedup 1.0000x reference)
//
#include <hip/hip_runtime.h>

#define E_ 8
#define H_ 1024
#define I_ 512
#define NE 9            // 8 routed + 1 shared
#define NTOK 8192
#define KC 4608         // 9*512 fused intermediate columns

typedef __bf16 bf16;
typedef __bf16 bf16x8 __attribute__((ext_vector_type(8)));
typedef __bf16 bf16x4 __attribute__((ext_vector_type(4)));
typedef float f32x4 __attribute__((ext_vector_type(4)));

__device__ __forceinline__ void gload16(const bf16* g, bf16* l) {
  __builtin_amdgcn_global_load_lds(
      (const __attribute__((address_space(1))) void*)g,
      (__attribute__((address_space(3))) void*)l,
      16, 0, 0);
}

// ---------------- x (fp32) -> Xb (bf16) ----------------
__global__ __launch_bounds__(256) void convert_kernel(
    const float* __restrict__ x, bf16* __restrict__ xb) {
  int i = blockIdx.x * 256 + threadIdx.x;       // one float4 per thread
  f32x4 v = ((const f32x4*)x)[i];
  bf16x4 o = {(bf16)v.x, (bf16)v.y, (bf16)v.z, (bf16)v.w};
  ((bf16x4*)xb)[i] = o;
}

// ---------------- router: cw[n, 0..8] (all fp32 math) ----------------
__global__ __launch_bounds__(256) void router_kernel(
    const float* __restrict__ x, const float* __restrict__ gw,
    const float* __restrict__ bias, float* __restrict__ cw) {
  int t = threadIdx.x;
  int l = t & 63, w = t >> 6;
  int n = blockIdx.x * 4 + w;
  const f32x4* xr = (const f32x4*)(x + (size_t)n * H_ + l * 16);
  float xv[16];
#pragma unroll
  for (int q = 0; q < 4; q++) {
    f32x4 v = xr[q];
    xv[q * 4 + 0] = v.x; xv[q * 4 + 1] = v.y; xv[q * 4 + 2] = v.z; xv[q * 4 + 3] = v.w;
  }
  float s[E_], sc[E_];
#pragma unroll
  for (int e = 0; e < E_; e++) {
    const f32x4* gr = (const f32x4*)(gw + e * H_ + l * 16);
    float acc = 0.f;
#pragma unroll
    for (int q = 0; q < 4; q++) {
      f32x4 g = gr[q];
      acc += xv[q * 4 + 0] * g.x + xv[q * 4 + 1] * g.y + xv[q * 4 + 2] * g.z + xv[q * 4 + 3] * g.w;
    }
#pragma unroll
    for (int off = 32; off > 0; off >>= 1) acc += __shfl_xor(acc, off, 64);
    float sig = 1.f / (1.f + __expf(-acc));
    s[e] = sig;
    sc[e] = sig + bias[e];
  }
  if (l == 0) {
    float gs[4];
#pragma unroll
    for (int g = 0; g < 4; g++) gs[g] = sc[2 * g] + sc[2 * g + 1];
    int g0 = 0;
    for (int g = 1; g < 4; g++) if (gs[g] > gs[g0]) g0 = g;       // stable argmax
    int g1 = -1;
    for (int g = 0; g < 4; g++) {
      if (g == g0) continue;
      if (g1 < 0 || gs[g] > gs[g1]) g1 = g;
    }
    float outw[NE];
#pragma unroll
    for (int e = 0; e < E_; e++) outw[e] = 0.f;
    outw[8] = 1.f;
    int es[4] = {2 * g0, 2 * g0 + 1, 2 * g1, 2 * g1 + 1};
    float wsum = 1e-20f;
    for (int j = 0; j < 4; j++) wsum += s[es[j]];
    float inv = 2.5f / wsum;
    for (int j = 0; j < 4; j++) outw[es[j]] = s[es[j]] * inv;
#pragma unroll
    for (int e = 0; e < NE; e++) cw[(size_t)n * NE + e] = outw[e];
  }
}

// ---------------- weight transpose + fp32->bf16 convert ----------------
// jobs 0..8 : Wg[e] (e=8 -> Wg_s)  [1024,512]  -> BgT[e] [512,1024]
// jobs 9..17: Wu family same
// jobs 18..26: Wd[e] (e=8 -> Wd_s) [512,1024] -> WdT [1024,4608] cols e*512..
__global__ __launch_bounds__(256) void transpose_kernel(
    const float* __restrict__ Wg, const float* __restrict__ Wu,
    const float* __restrict__ Wd, const float* __restrict__ Wgs,
    const float* __restrict__ Wus, const float* __restrict__ Wds,
    bf16* __restrict__ BgT, bf16* __restrict__ BuT, bf16* __restrict__ WdT) {
  __shared__ bf16 tile[32][33];
  int job = blockIdx.x >> 9;
  int tl = blockIdx.x & 511;
  const float* src;
  bf16* dst;
  int C, dst_ld;
  if (job < 18) {
    int e = job % 9;
    if (job < 9) src = (e < 8) ? Wg + (size_t)e * H_ * I_ : Wgs;
    else         src = (e < 8) ? Wu + (size_t)e * H_ * I_ : Wus;
    dst = ((job < 9) ? BgT : BuT) + (size_t)e * I_ * H_;
    C = I_; dst_ld = H_;            // src [1024,512] -> dst [512,1024]
  } else {
    int e = job - 18;
    src = (e < 8) ? Wd + (size_t)e * I_ * H_ : Wds;   // [512,1024]
    dst = WdT + (size_t)e * I_;     // into [1024,4608], col offset e*512
    C = H_; dst_ld = KC;
  }
  int n_tc = C >> 5;
  int tr = tl / n_tc, tc = tl % n_tc;
  int tx = threadIdx.x & 31, ty = threadIdx.x >> 5;
#pragma unroll
  for (int j = 0; j < 4; j++) {
    int r = tr * 32 + ty + j * 8;
    tile[ty + j * 8][tx] = (bf16)src[(size_t)r * C + tc * 32 + tx];
  }
  __syncthreads();
#pragma unroll
  for (int j = 0; j < 4; j++) {
    int c = tc * 32 + ty + j * 8;
    dst[(size_t)c * dst_ld + tr * 32 + tx] = tile[tx][ty + j * 8];
  }
}

// ---------------- GEMM1: T'[8192,4608] = cw * silu(X Wg) * (X Wu) ----------------
__global__ __launch_bounds__(256, 2) void gemm1_kernel(
    const bf16* __restrict__ X, const bf16* __restrict__ BgT,
    const bf16* __restrict__ BuT, const float* __restrict__ cw,
    bf16* __restrict__ Tp) {
  __shared__ bf16 As[128 * 64], Bgs[128 * 64], Bus[128 * 64];
  int t = threadIdx.x;
  int l = t & 63, w = t >> 6;
  int wm = w >> 1, wn = w & 1;
  int m0 = blockIdx.y * 128;
  int n0 = blockIdx.x * 128;
  int e = n0 >> 9;

  f32x4 accg[4][4], accu[4][4];
#pragma unroll
  for (int mi = 0; mi < 4; mi++)
#pragma unroll
    for (int ni = 0; ni < 4; ni++) {
      accg[mi][ni] = (f32x4){0.f, 0.f, 0.f, 0.f};
      accu[mi][ni] = (f32x4){0.f, 0.f, 0.f, 0.f};
    }

  int srow = t >> 3, scol = (t & 7) * 8;
  const bf16* ga = X + (size_t)(m0 + srow) * H_ + scol;
  const bf16* gg = BgT + (size_t)(n0 + srow) * H_ + scol;
  const bf16* gu = BuT + (size_t)(n0 + srow) * H_ + scol;
  bf16* la = As + w * 512;
  bf16* lg = Bgs + w * 512;
  bf16* lu = Bus + w * 512;

  for (int k0 = 0; k0 < H_; k0 += 64) {
#pragma unroll
    for (int i = 0; i < 4; i++) {
      gload16(ga + (size_t)i * 32 * H_ + k0, la + i * 2048);
      gload16(gg + (size_t)i * 32 * H_ + k0, lg + i * 2048);
      gload16(gu + (size_t)i * 32 * H_ + k0, lu + i * 2048);
    }
    __syncthreads();
#pragma unroll
    for (int ks = 0; ks < 2; ks++) {
      int ko = ks * 32 + (l >> 4) * 8;
      int ar = wm * 64 + (l & 15);
      int br = wn * 64 + (l & 15);
      bf16x8 af[4], bg[4], bu[4];
#pragma unroll
      for (int mi = 0; mi < 4; mi++)
        af[mi] = *(const bf16x8*)(As + (ar + mi * 16) * 64 + ko);
#pragma unroll
      for (int ni = 0; ni < 4; ni++) {
        bg[ni] = *(const bf16x8*)(Bgs + (br + ni * 16) * 64 + ko);
        bu[ni] = *(const bf16x8*)(Bus + (br + ni * 16) * 64 + ko);
      }
#pragma unroll
      for (int mi = 0; mi < 4; mi++)
#pragma unroll
        for (int ni = 0; ni < 4; ni++) {
          accg[mi][ni] = __builtin_amdgcn_mfma_f32_16x16x32_bf16(af[mi], bg[ni], accg[mi][ni], 0, 0, 0);
          accu[mi][ni] = __builtin_amdgcn_mfma_f32_16x16x32_bf16(af[mi], bu[ni], accu[mi][ni], 0, 0, 0);
        }
    }
    __syncthreads();
  }
#pragma unroll
  for (int mi = 0; mi < 4; mi++) {
#pragma unroll
    for (int r = 0; r < 4; r++) {
      int row = m0 + wm * 64 + mi * 16 + (l >> 4) * 4 + r;
      float c = cw[(size_t)row * NE + e];
#pragma unroll
      for (int ni = 0; ni < 4; ni++) {
        float g = accg[mi][ni][r];
        float u = accu[mi][ni][r];
        float val = c * (g / (1.f + __expf(-g))) * u;
        int col = n0 + wn * 64 + ni * 16 + (l & 15);
        Tp[(size_t)row * KC + col] = (bf16)val;
      }
    }
  }
}

// ---------------- GEMM2: out[8192,1024] = T' @ WdT^T (fp32 out) ----------------
__global__ __launch_bounds__(256, 3) void gemm2_kernel(
    const bf16* __restrict__ Tp, const bf16* __restrict__ WdT,
    float* __restrict__ out) {
  __shared__ bf16 As[128 * 64], Bs[128 * 64];
  int t = threadIdx.x;
  int l = t & 63, w = t >> 6;
  int wm = w >> 1, wn = w & 1;
  int m0 = blockIdx.y * 128;
  int n0 = blockIdx.x * 128;

  f32x4 acc[4][4];
#pragma unroll
  for (int mi = 0; mi < 4; mi++)
#pragma unroll
    for (int ni = 0; ni < 4; ni++) acc[mi][ni] = (f32x4){0.f, 0.f, 0.f, 0.f};

  int srow = t >> 3, scol = (t & 7) * 8;
  const bf16* ga = Tp + (size_t)(m0 + srow) * KC + scol;
  const bf16* gb = WdT + (size_t)(n0 + srow) * KC + scol;
  bf16* la = As + w * 512;
  bf16* lb = Bs + w * 512;

  for (int k0 = 0; k0 < KC; k0 += 64) {
#pragma unroll
    for (int i = 0; i < 4; i++) {
      gload16(ga + (size_t)i * 32 * KC + k0, la + i * 2048);
      gload16(gb + (size_t)i * 32 * KC + k0, lb + i * 2048);
    }
    __syncthreads();
#pragma unroll
    for (int ks = 0; ks < 2; ks++) {
      int ko = ks * 32 + (l >> 4) * 8;
      int ar = wm * 64 + (l & 15);
      int br = wn * 64 + (l & 15);
      bf16x8 af[4], bfv[4];
#pragma unroll
      for (int mi = 0; mi < 4; mi++)
        af[mi] = *(const bf16x8*)(As + (ar + mi * 16) * 64 + ko);
#pragma unroll
      for (int ni = 0; ni < 4; ni++)
        bfv[ni] = *(const bf16x8*)(Bs + (br + ni * 16) * 64 + ko);
#pragma unroll
      for (int mi = 0; mi < 4; mi++)
#pragma unroll
        for (int ni = 0; ni < 4; ni++)
          acc[mi][ni] = __builtin_amdgcn_mfma_f32_16x16x32_bf16(af[mi], bfv[ni], acc[mi][ni], 0, 0, 0);
    }
    __syncthreads();
  }
#pragma unroll
  for (int mi = 0; mi < 4; mi++) {
#pragma unroll
    for (int r = 0; r < 4; r++) {
      int row = m0 + wm * 64 + mi * 16 + (l >> 4) * 4 + r;
#pragma unroll
      for (int ni = 0; ni < 4; ni++) {
        int col = n0 + wn * 64 + ni * 16 + (l & 15);
        out[(size_t)row * H_ + col] = acc[mi][ni][r];
      }
    }
  }
}

extern "C" void kernel_launch(void* const* d_in, const int* in_sizes, int n_in,
                              void* d_out, int out_size, void* d_ws, size_t ws_size,
                              hipStream_t stream) {
  const float* x   = (const float*)d_in[0];
  const float* gw  = (const float*)d_in[1];
  const float* cb  = (const float*)d_in[2];
  const float* Wg  = (const float*)d_in[3];
  const float* Wu  = (const float*)d_in[4];
  const float* Wd  = (const float*)d_in[5];
  const float* Wgs = (const float*)d_in[6];
  const float* Wus = (const float*)d_in[7];
  const float* Wds = (const float*)d_in[8];

  char* ws = (char*)d_ws;
  size_t off = 0;
  float* cw = (float*)(ws + off); off += (size_t)NTOK * NE * 4;          // 294912
  bf16* BgT = (bf16*)(ws + off);  off += (size_t)NE * I_ * H_ * 2;       // 9437184
  bf16* BuT = (bf16*)(ws + off);  off += (size_t)NE * I_ * H_ * 2;
  bf16* WdT = (bf16*)(ws + off);  off += (size_t)H_ * KC * 2;            // 9437184
  bf16* Xb  = (bf16*)(ws + off);  off += (size_t)NTOK * H_ * 2;          // 16777216
  bf16* Tp  = (bf16*)(ws + off);  off += (size_t)NTOK * KC * 2;          // 75497472

  hipLaunchKernelGGL(convert_kernel, dim3(NTOK * H_ / 1024), dim3(256), 0, stream,
                     x, Xb);
  hipLaunchKernelGGL(transpose_kernel, dim3(27 * 512), dim3(256), 0, stream,
                     Wg, Wu, Wd, Wgs, Wus, Wds, BgT, BuT, WdT);
  hipLaunchKernelGGL(router_kernel, dim3(NTOK / 4), dim3(256), 0, stream,
                     x, gw, cb, cw);
  hipLaunchKernelGGL(gemm1_kernel, dim3(KC / 128, NTOK / 128), dim3(256), 0, stream,
                     Xb, BgT, BuT, cw, Tp);
  hipLaunchKernelGGL(gemm2_kernel, dim3(H_ / 128, NTOK / 128), dim3(256), 0, stream,
                     Tp, WdT, (float*)d_out);
}

// Round 3
// 402.826 us; speedup vs baseline: 1.0996x; 1.0996x over previous
//
#include <hip/hip_runtime.h>

#define E_ 8
#define H_ 1024
#define I_ 512
#define NE 9            // 8 routed + 1 shared
#define NTOK 8192
#define KC 4608         // 9*512 fused intermediate columns

typedef __bf16 bf16;
typedef __bf16 bf16x8 __attribute__((ext_vector_type(8)));
typedef __bf16 bf16x4 __attribute__((ext_vector_type(4)));
typedef float f32x4 __attribute__((ext_vector_type(4)));

__device__ __forceinline__ void gload16(const bf16* g, bf16* l) {
  __builtin_amdgcn_global_load_lds(
      (const __attribute__((address_space(1))) void*)g,
      (__attribute__((address_space(3))) void*)l,
      16, 0, 0);
}

// ---------------- x (fp32) -> Xb (bf16) ----------------
__global__ __launch_bounds__(256) void convert_kernel(
    const float* __restrict__ x, bf16* __restrict__ xb) {
  int i = blockIdx.x * 256 + threadIdx.x;       // one float4 per thread
  f32x4 v = ((const f32x4*)x)[i];
  bf16x4 o = {(bf16)v.x, (bf16)v.y, (bf16)v.z, (bf16)v.w};
  ((bf16x4*)xb)[i] = o;
}

// ---------------- router: cw[n, 0..8] (all fp32 math) ----------------
__global__ __launch_bounds__(256) void router_kernel(
    const float* __restrict__ x, const float* __restrict__ gw,
    const float* __restrict__ bias, float* __restrict__ cw) {
  int t = threadIdx.x;
  int l = t & 63, w = t >> 6;
  int n = blockIdx.x * 4 + w;
  const f32x4* xr = (const f32x4*)(x + (size_t)n * H_ + l * 16);
  float xv[16];
#pragma unroll
  for (int q = 0; q < 4; q++) {
    f32x4 v = xr[q];
    xv[q * 4 + 0] = v.x; xv[q * 4 + 1] = v.y; xv[q * 4 + 2] = v.z; xv[q * 4 + 3] = v.w;
  }
  float s[E_], sc[E_];
#pragma unroll
  for (int e = 0; e < E_; e++) {
    const f32x4* gr = (const f32x4*)(gw + e * H_ + l * 16);
    float acc = 0.f;
#pragma unroll
    for (int q = 0; q < 4; q++) {
      f32x4 g = gr[q];
      acc += xv[q * 4 + 0] * g.x + xv[q * 4 + 1] * g.y + xv[q * 4 + 2] * g.z + xv[q * 4 + 3] * g.w;
    }
#pragma unroll
    for (int off = 32; off > 0; off >>= 1) acc += __shfl_xor(acc, off, 64);
    float sig = 1.f / (1.f + __expf(-acc));
    s[e] = sig;
    sc[e] = sig + bias[e];
  }
  if (l == 0) {
    float gs[4];
#pragma unroll
    for (int g = 0; g < 4; g++) gs[g] = sc[2 * g] + sc[2 * g + 1];
    int g0 = 0;
    for (int g = 1; g < 4; g++) if (gs[g] > gs[g0]) g0 = g;       // stable argmax
    int g1 = -1;
    for (int g = 0; g < 4; g++) {
      if (g == g0) continue;
      if (g1 < 0 || gs[g] > gs[g1]) g1 = g;
    }
    float outw[NE];
#pragma unroll
    for (int e = 0; e < E_; e++) outw[e] = 0.f;
    outw[8] = 1.f;
    int es[4] = {2 * g0, 2 * g0 + 1, 2 * g1, 2 * g1 + 1};
    float wsum = 1e-20f;
    for (int j = 0; j < 4; j++) wsum += s[es[j]];
    float inv = 2.5f / wsum;
    for (int j = 0; j < 4; j++) outw[es[j]] = s[es[j]] * inv;
#pragma unroll
    for (int e = 0; e < NE; e++) cw[(size_t)n * NE + e] = outw[e];
  }
}

// ---------------- weight transpose + fp32->bf16 convert ----------------
__global__ __launch_bounds__(256) void transpose_kernel(
    const float* __restrict__ Wg, const float* __restrict__ Wu,
    const float* __restrict__ Wd, const float* __restrict__ Wgs,
    const float* __restrict__ Wus, const float* __restrict__ Wds,
    bf16* __restrict__ BgT, bf16* __restrict__ BuT, bf16* __restrict__ WdT) {
  __shared__ bf16 tile[32][33];
  int job = blockIdx.x >> 9;
  int tl = blockIdx.x & 511;
  const float* src;
  bf16* dst;
  int C, dst_ld;
  if (job < 18) {
    int e = job % 9;
    if (job < 9) src = (e < 8) ? Wg + (size_t)e * H_ * I_ : Wgs;
    else         src = (e < 8) ? Wu + (size_t)e * H_ * I_ : Wus;
    dst = ((job < 9) ? BgT : BuT) + (size_t)e * I_ * H_;
    C = I_; dst_ld = H_;            // src [1024,512] -> dst [512,1024]
  } else {
    int e = job - 18;
    src = (e < 8) ? Wd + (size_t)e * I_ * H_ : Wds;   // [512,1024]
    dst = WdT + (size_t)e * I_;     // into [1024,4608], col offset e*512
    C = H_; dst_ld = KC;
  }
  int n_tc = C >> 5;
  int tr = tl / n_tc, tc = tl % n_tc;
  int tx = threadIdx.x & 31, ty = threadIdx.x >> 5;
#pragma unroll
  for (int j = 0; j < 4; j++) {
    int r = tr * 32 + ty + j * 8;
    tile[ty + j * 8][tx] = (bf16)src[(size_t)r * C + tc * 32 + tx];
  }
  __syncthreads();
#pragma unroll
  for (int j = 0; j < 4; j++) {
    int c = tc * 32 + ty + j * 8;
    dst[(size_t)c * dst_ld + tr * 32 + tx] = tile[tx][ty + j * 8];
  }
}

// LDS tile layout (both GEMMs): [128 rows][64 cols] bf16, XOR-swizzled in
// 16B chunks: LDS[row][c] holds Global[row][c ^ (row&7)] (c = chunk 0..7).
// Staging lane l (wave w): row = w*8 + (l>>3) (+32 per i), LDS chunk = l&7
// (forced by global_load_lds), so global chunk = (l&7) ^ ((l>>3)&7).
// Fragment read of global chunk q at row r: LDS chunk = q ^ (r&7); all row
// offsets in the loops are multiples of 8, so swizzle = q ^ (l&7), a per-lane
// constant -> 16-way bank conflict becomes 2-way (free, m136).

// ---------------- GEMM1: T'[8192,4608] = cw * silu(X Wg) * (X Wu) ----------------
__global__ __launch_bounds__(256, 2) void gemm1_kernel(
    const bf16* __restrict__ X, const bf16* __restrict__ BgT,
    const bf16* __restrict__ BuT, const float* __restrict__ cw,
    bf16* __restrict__ Tp) {
  __shared__ bf16 As[128 * 64], Bgs[128 * 64], Bus[128 * 64];
  int t = threadIdx.x;
  int l = t & 63, w = t >> 6;
  int wm = w >> 1, wn = w & 1;
  int m0 = blockIdx.y * 128;
  int n0 = blockIdx.x * 128;
  int e = n0 >> 9;

  f32x4 accg[4][4], accu[4][4];
#pragma unroll
  for (int mi = 0; mi < 4; mi++)
#pragma unroll
    for (int ni = 0; ni < 4; ni++) {
      accg[mi][ni] = (f32x4){0.f, 0.f, 0.f, 0.f};
      accu[mi][ni] = (f32x4){0.f, 0.f, 0.f, 0.f};
    }

  int srow = t >> 3;
  int scol = (((t & 7) ^ ((t >> 3) & 7)) * 8);     // swizzled global chunk
  const bf16* ga = X + (size_t)(m0 + srow) * H_ + scol;
  const bf16* gg = BgT + (size_t)(n0 + srow) * H_ + scol;
  const bf16* gu = BuT + (size_t)(n0 + srow) * H_ + scol;
  bf16* la = As + w * 512;
  bf16* lg = Bgs + w * 512;
  bf16* lu = Bus + w * 512;

  for (int k0 = 0; k0 < H_; k0 += 64) {
#pragma unroll
    for (int i = 0; i < 4; i++) {
      gload16(ga + (size_t)i * 32 * H_ + k0, la + i * 2048);
      gload16(gg + (size_t)i * 32 * H_ + k0, lg + i * 2048);
      gload16(gu + (size_t)i * 32 * H_ + k0, lu + i * 2048);
    }
    __syncthreads();
#pragma unroll
    for (int ks = 0; ks < 2; ks++) {
      int ko = (((ks * 4 + (l >> 4)) ^ (l & 7)) * 8);   // swizzled read chunk
      int ar = wm * 64 + (l & 15);
      int br = wn * 64 + (l & 15);
      bf16x8 af[4], bg[4], bu[4];
#pragma unroll
      for (int mi = 0; mi < 4; mi++)
        af[mi] = *(const bf16x8*)(As + (ar + mi * 16) * 64 + ko);
#pragma unroll
      for (int ni = 0; ni < 4; ni++) {
        bg[ni] = *(const bf16x8*)(Bgs + (br + ni * 16) * 64 + ko);
        bu[ni] = *(const bf16x8*)(Bus + (br + ni * 16) * 64 + ko);
      }
#pragma unroll
      for (int mi = 0; mi < 4; mi++)
#pragma unroll
        for (int ni = 0; ni < 4; ni++) {
          accg[mi][ni] = __builtin_amdgcn_mfma_f32_16x16x32_bf16(af[mi], bg[ni], accg[mi][ni], 0, 0, 0);
          accu[mi][ni] = __builtin_amdgcn_mfma_f32_16x16x32_bf16(af[mi], bu[ni], accu[mi][ni], 0, 0, 0);
        }
    }
    __syncthreads();
  }
#pragma unroll
  for (int mi = 0; mi < 4; mi++) {
#pragma unroll
    for (int r = 0; r < 4; r++) {
      int row = m0 + wm * 64 + mi * 16 + (l >> 4) * 4 + r;
      float c = cw[(size_t)row * NE + e];
#pragma unroll
      for (int ni = 0; ni < 4; ni++) {
        float g = accg[mi][ni][r];
        float u = accu[mi][ni][r];
        float val = c * (g / (1.f + __expf(-g))) * u;
        int col = n0 + wn * 64 + ni * 16 + (l & 15);
        Tp[(size_t)row * KC + col] = (bf16)val;
      }
    }
  }
}

// ---------------- GEMM2: out[8192,1024] = T' @ WdT^T (fp32 out) ----------------
__global__ __launch_bounds__(256, 3) void gemm2_kernel(
    const bf16* __restrict__ Tp, const bf16* __restrict__ WdT,
    float* __restrict__ out) {
  __shared__ bf16 As[128 * 64], Bs[128 * 64];
  int t = threadIdx.x;
  int l = t & 63, w = t >> 6;
  int wm = w >> 1, wn = w & 1;
  int m0 = blockIdx.y * 128;
  int n0 = blockIdx.x * 128;

  f32x4 acc[4][4];
#pragma unroll
  for (int mi = 0; mi < 4; mi++)
#pragma unroll
    for (int ni = 0; ni < 4; ni++) acc[mi][ni] = (f32x4){0.f, 0.f, 0.f, 0.f};

  int srow = t >> 3;
  int scol = (((t & 7) ^ ((t >> 3) & 7)) * 8);
  const bf16* ga = Tp + (size_t)(m0 + srow) * KC + scol;
  const bf16* gb = WdT + (size_t)(n0 + srow) * KC + scol;
  bf16* la = As + w * 512;
  bf16* lb = Bs + w * 512;

  for (int k0 = 0; k0 < KC; k0 += 64) {
#pragma unroll
    for (int i = 0; i < 4; i++) {
      gload16(ga + (size_t)i * 32 * KC + k0, la + i * 2048);
      gload16(gb + (size_t)i * 32 * KC + k0, lb + i * 2048);
    }
    __syncthreads();
#pragma unroll
    for (int ks = 0; ks < 2; ks++) {
      int ko = (((ks * 4 + (l >> 4)) ^ (l & 7)) * 8);
      int ar = wm * 64 + (l & 15);
      int br = wn * 64 + (l & 15);
      bf16x8 af[4], bfv[4];
#pragma unroll
      for (int mi = 0; mi < 4; mi++)
        af[mi] = *(const bf16x8*)(As + (ar + mi * 16) * 64 + ko);
#pragma unroll
      for (int ni = 0; ni < 4; ni++)
        bfv[ni] = *(const bf16x8*)(Bs + (br + ni * 16) * 64 + ko);
#pragma unroll
      for (int mi = 0; mi < 4; mi++)
#pragma unroll
        for (int ni = 0; ni < 4; ni++)
          acc[mi][ni] = __builtin_amdgcn_mfma_f32_16x16x32_bf16(af[mi], bfv[ni], acc[mi][ni], 0, 0, 0);
    }
    __syncthreads();
  }
#pragma unroll
  for (int mi = 0; mi < 4; mi++) {
#pragma unroll
    for (int r = 0; r < 4; r++) {
      int row = m0 + wm * 64 + mi * 16 + (l >> 4) * 4 + r;
#pragma unroll
      for (int ni = 0; ni < 4; ni++) {
        int col = n0 + wn * 64 + ni * 16 + (l & 15);
        out[(size_t)row * H_ + col] = acc[mi][ni][r];
      }
    }
  }
}

extern "C" void kernel_launch(void* const* d_in, const int* in_sizes, int n_in,
                              void* d_out, int out_size, void* d_ws, size_t ws_size,
                              hipStream_t stream) {
  const float* x   = (const float*)d_in[0];
  const float* gw  = (const float*)d_in[1];
  const float* cb  = (const float*)d_in[2];
  const float* Wg  = (const float*)d_in[3];
  const float* Wu  = (const float*)d_in[4];
  const float* Wd  = (const float*)d_in[5];
  const float* Wgs = (const float*)d_in[6];
  const float* Wus = (const float*)d_in[7];
  const float* Wds = (const float*)d_in[8];

  char* ws = (char*)d_ws;
  size_t off = 0;
  float* cw = (float*)(ws + off); off += (size_t)NTOK * NE * 4;
  bf16* BgT = (bf16*)(ws + off);  off += (size_t)NE * I_ * H_ * 2;
  bf16* BuT = (bf16*)(ws + off);  off += (size_t)NE * I_ * H_ * 2;
  bf16* WdT = (bf16*)(ws + off);  off += (size_t)H_ * KC * 2;
  bf16* Xb  = (bf16*)(ws + off);  off += (size_t)NTOK * H_ * 2;
  bf16* Tp  = (bf16*)(ws + off);  off += (size_t)NTOK * KC * 2;

  hipLaunchKernelGGL(convert_kernel, dim3(NTOK * H_ / 1024), dim3(256), 0, stream,
                     x, Xb);
  hipLaunchKernelGGL(transpose_kernel, dim3(27 * 512), dim3(256), 0, stream,
                     Wg, Wu, Wd, Wgs, Wus, Wds, BgT, BuT, WdT);
  hipLaunchKernelGGL(router_kernel, dim3(NTOK / 4), dim3(256), 0, stream,
                     x, gw, cb, cw);
  hipLaunchKernelGGL(gemm1_kernel, dim3(KC / 128, NTOK / 128), dim3(256), 0, stream,
                     Xb, BgT, BuT, cw, Tp);
  hipLaunchKernelGGL(gemm2_kernel, dim3(H_ / 128, NTOK / 128), dim3(256), 0, stream,
                     Tp, WdT, (float*)d_out);
}